// Round 9
// baseline (111.477 us; speedup 1.0000x reference)
//
#include <hip/hip_runtime.h>

// Chamfer distance, B=8, N=M=8192, 3-D fp32 points — pre-encoded MFMA frags.
// d2 = xx + yy - 2x.y inside mfma_f32_32x32x16_bf16 via split-precision limbs
// packed along K (13/16 slots; absmax 0.0 in R4-R8):
//   A row (query q):  [(-2q)h*3, (-2q)l*3, (-2q)h*3, qqh, qql, 1, 1, 0,0,0]
//   B col (target t): [ th*3,     th*3,     tl*3,    1, 1, tth, ttl, 0,0,0]
// R9: vector-domain min accumulation — per col-tile a running f32x16 minvec,
// elementwise fmin per MFMA (16 independent ops, no scalar chains, no
// per-MFMA acc->scalar extraction). Scalar reduce once per kernel. R7 shape
// (CT=8, 512 blocks, 2 blocks/CU) which was the best so far.

#define BB 8
#define NN 8192
#define NPTS (BB*NN)  // 65536
#define BLK 256
#define CCOLS 256
#define CT 8          // col-tiles per block
#define RT 4          // row-tiles per strip per wave
#define STRIPS 16     // 16 strips * 4 waves * 128 rows = 8192
#define GRID 512      // 2 dir * 8 b * 32 cc

typedef __attribute__((ext_vector_type(8))) short bf16x8;
typedef __attribute__((ext_vector_type(16))) float f32x16;

__device__ __forceinline__ unsigned f2mono(float f) {
    unsigned u = __float_as_uint(f);
    return u ^ ((unsigned)((int)u >> 31) | 0x80000000u);
}
__device__ __forceinline__ float mono2f(unsigned m) {
    unsigned u = ((int)m >= 0) ? ~m : (m ^ 0x80000000u);
    return __uint_as_float(u);
}
__device__ __forceinline__ unsigned bfh(float v) {   // fp32 -> bf16 RNE
    unsigned u = __float_as_uint(v);
    u += 0x7FFFu + ((u >> 16) & 1u);
    return u >> 16;
}
__device__ __forceinline__ float bff(unsigned h) {
    return __uint_as_float(h << 16);
}
__device__ __forceinline__ unsigned pk(unsigned lo, unsigned hi) {
    return (lo & 0xFFFFu) | (hi << 16);
}

// grid 512, block 256: one thread per point (x: [0,NPTS), y: [NPTS,2*NPTS))
__global__ void prep_kernel(const float* __restrict__ x, const float* __restrict__ y,
                            uint4* __restrict__ afr, uint4* __restrict__ bfr,
                            unsigned* __restrict__ counter) {
    int i = blockIdx.x * BLK + threadIdx.x;
    if (i == 0) *counter = 0;
    const float* src = (i < NPTS) ? x : y;
    int j = (i < NPTS) ? i : i - NPTS;
    float c0 = src[3*j], c1 = src[3*j+1], c2 = src[3*j+2];
    float s2 = c0*c0 + c1*c1 + c2*c2;
    unsigned sh = bfh(s2), sl = bfh(s2 - bff(sh));
    float a0 = -2.f*c0, a1 = -2.f*c1, a2 = -2.f*c2;
    unsigned ah0 = bfh(a0), ah1 = bfh(a1), ah2 = bfh(a2);
    unsigned al0 = bfh(a0 - bff(ah0)), al1 = bfh(a1 - bff(ah1)), al2 = bfh(a2 - bff(ah2));
    unsigned bh0 = bfh(c0), bh1 = bfh(c1), bh2 = bfh(c2);
    unsigned bl0 = bfh(c0 - bff(bh0)), bl1 = bfh(c1 - bff(bh1)), bl2 = bfh(c2 - bff(bh2));
    const unsigned one = 0x3F80u;
    afr[2*i]   = make_uint4(pk(ah0,ah1), pk(ah2,al0), pk(al1,al2), pk(ah0,ah1));
    afr[2*i+1] = make_uint4(pk(ah2,sh),  pk(sl,one),  pk(one,0u),  0u);
    bfr[2*i]   = make_uint4(pk(bh0,bh1), pk(bh2,bh0), pk(bh1,bh2), pk(bl0,bl1));
    bfr[2*i+1] = make_uint4(pk(bl2,one), pk(one,sh),  pk(sl,0u),   0u);
}

__device__ __forceinline__ bf16x8 cvt(uint4 v) { return __builtin_bit_cast(bf16x8, v); }
__device__ __forceinline__ f32x16 vmin16(f32x16 a, f32x16 b) {
    f32x16 r;
#pragma unroll
    for (int i = 0; i < 16; ++i) r[i] = fminf(a[i], b[i]);
    return r;
}

// grid: 512 = (dir<<8) | (b<<5) | cc ; block 256
__global__ __launch_bounds__(BLK, 2) void
main_kernel(const uint4* __restrict__ afr, const uint4* __restrict__ bfr,
            float* __restrict__ bpart, unsigned* __restrict__ counter,
            float* __restrict__ out) {
    __shared__ unsigned colmin[CCOLS];
    __shared__ float red[4];
    __shared__ float gg[16];
    __shared__ int lastflag;
    const int bi  = blockIdx.x;
    const int dir = bi >> 8;
    const int b   = (bi >> 5) & 7;
    const int cc  = bi & 31;
    const uint4* Af = afr + (dir ? 2*NPTS : 0);        // A rows: dir? y : x
    const uint4* Bf = bfr + (dir ? 0 : 2*NPTS);        // B cols: dir? x : y
    const int tid = threadIdx.x;
    const int lane = tid & 63, w = tid >> 6;
    const int m = lane & 31;
    const int hb = lane >> 5;

    colmin[tid] = 0xFFFFFFFFu;       // barrier after the hot loop

    // this block's 8 B col-tile fragments -> registers (coalesced dwordx4)
    bf16x8 bf[CT];
#pragma unroll
    for (int ct = 0; ct < CT; ++ct) {
        int c = b * NN + cc * CCOLS + ct * 32 + m;
        bf[ct] = cvt(Bf[2*c + hb]);
    }

    f32x16 zro;
#pragma unroll
    for (int i = 0; i < 16; ++i) zro[i] = 0.f;

    f32x16 vm[CT];
#pragma unroll
    for (int ct = 0; ct < CT; ++ct) vm[ct] = zro + 3.4e38f;

    const int rowbase = b * NN + w * 128 + m;
    uint4 cur[RT], nxt[RT];
#pragma unroll
    for (int t = 0; t < RT; ++t) cur[t] = Af[2*(rowbase + t*32) + hb];

#pragma unroll 1
    for (int s = 0; s < STRIPS; ++s) {
        const int np = (s + 1 < STRIPS) ? (s + 1) : s;   // prefetch next strip
#pragma unroll
        for (int t = 0; t < RT; ++t) nxt[t] = Af[2*(rowbase + np*512 + t*32) + hb];
#pragma unroll
        for (int t = 0; t < RT; ++t) {       // t outer: vm[ct] deps 8 MFMAs apart
            bf16x8 av = cvt(cur[t]);
#pragma unroll
            for (int ct = 0; ct < CT; ++ct) {
                f32x16 acc = __builtin_amdgcn_mfma_f32_32x32x16_bf16(av, bf[ct], zro, 0, 0, 0);
                vm[ct] = vmin16(vm[ct], acc);    // 16 independent v_min_f32
            }
        }
#pragma unroll
        for (int t = 0; t < RT; ++t) cur[t] = nxt[t];
    }

    // scalar-reduce each col-tile's minvec ONCE, merge K-halves, LDS combine
#pragma unroll
    for (int ct = 0; ct < CT; ++ct) {
        f32x16 v = vm[ct];
        float p0 = fminf(fminf(v[0], v[1]), fminf(v[2], v[3]));
        float p1 = fminf(fminf(v[4], v[5]), fminf(v[6], v[7]));
        float p2 = fminf(fminf(v[8], v[9]), fminf(v[10], v[11]));
        float p3 = fminf(fminf(v[12], v[13]), fminf(v[14], v[15]));
        float p = fminf(fminf(p0, p1), fminf(p2, p3));
        p = fminf(p, __shfl_xor(p, 32, 64));
        if (hb == 0) atomicMin(&colmin[ct * 32 + m], f2mono(p));
    }
    __syncthreads();

    // colmin[tid] is the FINAL min-d2 for col (cc*256 + tid)
    float d = sqrtf(fmaxf(mono2f(colmin[tid]), 0.f) + 1e-10f);
#pragma unroll
    for (int off = 32; off; off >>= 1) d += __shfl_down(d, off, 64);
    if (lane == 0) red[w] = d;
    __syncthreads();
    if (tid == 0) {
        float total = red[0] + red[1] + red[2] + red[3];
        atomicExch(&bpart[bi], total);        // device-scope coherent store
        __threadfence();
        unsigned old = atomicAdd(counter, 1u);
        lastflag = (old == GRID - 1);
    }
    __syncthreads();

    if (lastflag) {                           // block-uniform
        float v0 = atomicAdd(&bpart[tid], 0.f);        // dir=0, group=tid>>5
        float v1 = atomicAdd(&bpart[256 + tid], 0.f);  // dir=1
#pragma unroll
        for (int off = 16; off; off >>= 1) {
            v0 += __shfl_down(v0, off, 32);
            v1 += __shfl_down(v1, off, 32);
        }
        if ((tid & 31) == 0) gg[tid >> 5] = fmaxf(v0, v1);
        __syncthreads();
        if (tid == 0) {
            float acc = 0.f;
#pragma unroll
            for (int k = 0; k < 8; ++k) acc += gg[k];
            out[0] = acc * (1.0f / (float)NN);
        }
    }
}

extern "C" void kernel_launch(void* const* d_in, const int* in_sizes, int n_in,
                              void* d_out, int out_size, void* d_ws, size_t ws_size,
                              hipStream_t stream) {
    const float* x = (const float*)d_in[0];
    const float* y = (const float*)d_in[1];
    float* out = (float*)d_out;

    char* ws = (char*)d_ws;
    uint4* afr = (uint4*)ws;                     // 2*NPTS*2 uint4 = 4 MB
    uint4* bfr = afr + 4 * NPTS;                 // 4 MB
    float* bpart = (float*)(bfr + 4 * NPTS);     // 512 floats
    unsigned* counter = (unsigned*)(bpart + GRID);

    prep_kernel<<<(2 * NPTS) / BLK, BLK, 0, stream>>>(x, y, afr, bfr, counter);
    main_kernel<<<GRID, BLK, 0, stream>>>(afr, bfr, bpart, counter, out);
}

// Round 10
// 110.080 us; speedup vs baseline: 1.0127x; 1.0127x over previous
//
#include <hip/hip_runtime.h>

// Chamfer distance, B=8, N=M=8192, 3-D fp32 points — pre-encoded MFMA frags.
// d2 = xx + yy - 2x.y inside mfma_f32_32x32x16_bf16 via split-precision limbs
// packed along K (13/16 slots; absmax 0.0 in R4-R9):
//   A row (query q):  [(-2q)h*3, (-2q)l*3, (-2q)h*3, qqh, qql, 1, 1, 0,0,0]
//   B col (target t): [ th*3,     th*3,     tl*3,    1, 1, tth, ttl, 0,0,0]
// R10: vector-domain min (16 independent v_min_f32 per MFMA — the minimal
// epilogue) with registers SIZED TO FIT: CT=4 -> vm is 64 regs, total ~170
// live < 256 cap (R9's CT=8 demanded ~240 @cap128 -> 23MB scratch spill).
// Explicit 2-slot acc pipeline hides MFMA latency. GRID=1024.

#define BB 8
#define NN 8192
#define NPTS (BB*NN)  // 65536
#define BLK 256
#define CCOLS 128
#define CT 4          // col-tiles per block
#define RT 4          // row-tiles per strip per wave
#define STRIPS 16     // 16 strips * 4 waves * 128 rows = 8192
#define GRID 1024     // 2 dir * 8 b * 64 cc

typedef __attribute__((ext_vector_type(8))) short bf16x8;
typedef __attribute__((ext_vector_type(16))) float f32x16;

__device__ __forceinline__ unsigned f2mono(float f) {
    unsigned u = __float_as_uint(f);
    return u ^ ((unsigned)((int)u >> 31) | 0x80000000u);
}
__device__ __forceinline__ float mono2f(unsigned m) {
    unsigned u = ((int)m >= 0) ? ~m : (m ^ 0x80000000u);
    return __uint_as_float(u);
}
__device__ __forceinline__ unsigned bfh(float v) {   // fp32 -> bf16 RNE
    unsigned u = __float_as_uint(v);
    u += 0x7FFFu + ((u >> 16) & 1u);
    return u >> 16;
}
__device__ __forceinline__ float bff(unsigned h) {
    return __uint_as_float(h << 16);
}
__device__ __forceinline__ unsigned pk(unsigned lo, unsigned hi) {
    return (lo & 0xFFFFu) | (hi << 16);
}

// grid 512, block 256: one thread per point (x: [0,NPTS), y: [NPTS,2*NPTS))
__global__ void prep_kernel(const float* __restrict__ x, const float* __restrict__ y,
                            uint4* __restrict__ afr, uint4* __restrict__ bfr,
                            unsigned* __restrict__ counter) {
    int i = blockIdx.x * BLK + threadIdx.x;
    if (i == 0) *counter = 0;
    const float* src = (i < NPTS) ? x : y;
    int j = (i < NPTS) ? i : i - NPTS;
    float c0 = src[3*j], c1 = src[3*j+1], c2 = src[3*j+2];
    float s2 = c0*c0 + c1*c1 + c2*c2;
    unsigned sh = bfh(s2), sl = bfh(s2 - bff(sh));
    float a0 = -2.f*c0, a1 = -2.f*c1, a2 = -2.f*c2;
    unsigned ah0 = bfh(a0), ah1 = bfh(a1), ah2 = bfh(a2);
    unsigned al0 = bfh(a0 - bff(ah0)), al1 = bfh(a1 - bff(ah1)), al2 = bfh(a2 - bff(ah2));
    unsigned bh0 = bfh(c0), bh1 = bfh(c1), bh2 = bfh(c2);
    unsigned bl0 = bfh(c0 - bff(bh0)), bl1 = bfh(c1 - bff(bh1)), bl2 = bfh(c2 - bff(bh2));
    const unsigned one = 0x3F80u;
    afr[2*i]   = make_uint4(pk(ah0,ah1), pk(ah2,al0), pk(al1,al2), pk(ah0,ah1));
    afr[2*i+1] = make_uint4(pk(ah2,sh),  pk(sl,one),  pk(one,0u),  0u);
    bfr[2*i]   = make_uint4(pk(bh0,bh1), pk(bh2,bh0), pk(bh1,bh2), pk(bl0,bl1));
    bfr[2*i+1] = make_uint4(pk(bl2,one), pk(one,sh),  pk(sl,0u),   0u);
}

__device__ __forceinline__ bf16x8 cvt(uint4 v) { return __builtin_bit_cast(bf16x8, v); }
__device__ __forceinline__ f32x16 vmin16(f32x16 a, f32x16 b) {
    f32x16 r;
#pragma unroll
    for (int i = 0; i < 16; ++i) r[i] = fminf(a[i], b[i]);
    return r;
}

// grid: 1024 = (dir<<9) | (b<<6) | cc ; block 256
__global__ __launch_bounds__(BLK, 2) void
main_kernel(const uint4* __restrict__ afr, const uint4* __restrict__ bfr,
            float* __restrict__ bpart, unsigned* __restrict__ counter,
            float* __restrict__ out) {
    __shared__ unsigned colmin[CCOLS];
    __shared__ float red[4];
    __shared__ float gg[16];
    __shared__ int lastflag;
    const int bi  = blockIdx.x;
    const int dir = bi >> 9;
    const int b   = (bi >> 6) & 7;
    const int cc  = bi & 63;
    const uint4* Af = afr + (dir ? 2*NPTS : 0);        // A rows: dir? y : x
    const uint4* Bf = bfr + (dir ? 0 : 2*NPTS);        // B cols: dir? x : y
    const int tid = threadIdx.x;
    const int lane = tid & 63, w = tid >> 6;
    const int m = lane & 31;
    const int hb = lane >> 5;

    if (tid < CCOLS) colmin[tid] = 0xFFFFFFFFu;  // barrier after the hot loop

    // this block's 4 B col-tile fragments -> registers (coalesced dwordx4)
    bf16x8 bf[CT];
#pragma unroll
    for (int ct = 0; ct < CT; ++ct) {
        int c = b * NN + cc * CCOLS + ct * 32 + m;
        bf[ct] = cvt(Bf[2*c + hb]);
    }

    f32x16 zro;
#pragma unroll
    for (int i = 0; i < 16; ++i) zro[i] = 0.f;

    f32x16 vm[CT];
#pragma unroll
    for (int ct = 0; ct < CT; ++ct) vm[ct] = zro + 3.4e38f;

    const int rowbase = b * NN + w * 128 + m;
    uint4 cur[RT], nxt[RT];
#pragma unroll
    for (int t = 0; t < RT; ++t) cur[t] = Af[2*(rowbase + t*32) + hb];

#pragma unroll 1
    for (int s = 0; s < STRIPS; ++s) {
        const int np = (s + 1 < STRIPS) ? (s + 1) : s;   // prefetch next strip
#pragma unroll
        for (int t = 0; t < RT; ++t) nxt[t] = Af[2*(rowbase + np*512 + t*32) + hb];

        // 16 MFMAs, 2-slot pipeline: issue i+1, consume i
        f32x16 accA = __builtin_amdgcn_mfma_f32_32x32x16_bf16(cvt(cur[0]), bf[0], zro, 0, 0, 0);
#pragma unroll
        for (int i = 0; i < RT * CT - 1; ++i) {
            f32x16 accB = __builtin_amdgcn_mfma_f32_32x32x16_bf16(
                cvt(cur[(i + 1) >> 2]), bf[(i + 1) & 3], zro, 0, 0, 0);
            vm[i & 3] = vmin16(vm[i & 3], accA);   // 16 independent v_min_f32
            accA = accB;
        }
        vm[3] = vmin16(vm[3], accA);

#pragma unroll
        for (int t = 0; t < RT; ++t) cur[t] = nxt[t];
    }

    // scalar-reduce each col-tile's minvec ONCE, merge K-halves, LDS combine
#pragma unroll
    for (int ct = 0; ct < CT; ++ct) {
        f32x16 v = vm[ct];
        float p0 = fminf(fminf(v[0], v[1]), fminf(v[2], v[3]));
        float p1 = fminf(fminf(v[4], v[5]), fminf(v[6], v[7]));
        float p2 = fminf(fminf(v[8], v[9]), fminf(v[10], v[11]));
        float p3 = fminf(fminf(v[12], v[13]), fminf(v[14], v[15]));
        float p = fminf(fminf(p0, p1), fminf(p2, p3));
        p = fminf(p, __shfl_xor(p, 32, 64));
        if (hb == 0) atomicMin(&colmin[ct * 32 + m], f2mono(p));
    }
    __syncthreads();

    // colmin[c] is the FINAL min-d2 for col (cc*128 + c)
    float d = 0.f;
    if (tid < CCOLS) d = sqrtf(fmaxf(mono2f(colmin[tid]), 0.f) + 1e-10f);
#pragma unroll
    for (int off = 32; off; off >>= 1) d += __shfl_down(d, off, 64);
    if (lane == 0) red[w] = d;
    __syncthreads();
    if (tid == 0) {
        float total = red[0] + red[1] + red[2] + red[3];
        atomicExch(&bpart[bi], total);        // device-scope coherent store
        __threadfence();
        unsigned old = atomicAdd(counter, 1u);
        lastflag = (old == GRID - 1);
    }
    __syncthreads();

    if (lastflag) {                           // block-uniform
        // bpart layout: bi = g*64 + cc with g = dir*8+b (16 groups of 64)
        const int g = tid >> 4, k = tid & 15;
        float v = 0.f;
#pragma unroll
        for (int j = 0; j < 4; ++j)
            v += atomicAdd(&bpart[g * 64 + k * 4 + j], 0.f);   // coherent read
#pragma unroll
        for (int off = 8; off; off >>= 1) v += __shfl_down(v, off, 16);
        if (k == 0) gg[g] = v;
        __syncthreads();
        if (tid == 0) {
            float acc = 0.f;
#pragma unroll
            for (int bb = 0; bb < BB; ++bb) acc += fmaxf(gg[bb], gg[BB + bb]);
            out[0] = acc * (1.0f / (float)NN);
        }
    }
}

extern "C" void kernel_launch(void* const* d_in, const int* in_sizes, int n_in,
                              void* d_out, int out_size, void* d_ws, size_t ws_size,
                              hipStream_t stream) {
    const float* x = (const float*)d_in[0];
    const float* y = (const float*)d_in[1];
    float* out = (float*)d_out;

    char* ws = (char*)d_ws;
    uint4* afr = (uint4*)ws;                     // 2*NPTS*2 uint4 = 4 MB
    uint4* bfr = afr + 4 * NPTS;                 // 4 MB
    float* bpart = (float*)(bfr + 4 * NPTS);     // 1024 floats
    unsigned* counter = (unsigned*)(bpart + GRID);

    prep_kernel<<<(2 * NPTS) / BLK, BLK, 0, stream>>>(x, y, afr, bfr, counter);
    main_kernel<<<GRID, BLK, 0, stream>>>(afr, bfr, bpart, counter, out);
}